// Round 12
// baseline (130.718 us; speedup 1.0000x reference)
//
#include <hip/hip_runtime.h>

// Self-attention fwd, B=2 N=2048 H=16 D=64, fp32 in/out, bf16 MFMA compute.
// Round 19: anti-phase wave pairing.
//   Plateau evidence: R12/R16/R18 all ~47 us with VALU ~37 + MFMA ~30
//   (67% combined, 33% stall) at 2 waves/SIMD. Intra-wave reordering is
//   exhausted; the 2 co-resident waves per SIMD (same w, different blocks)
//   run the same QK->SM->PV sequence in near-lockstep and contend for the
//   same pipe instead of filling each other's gaps.
//   Fix: 256 blocks x 512 threads (8 waves). Wave w -> SIMD w&3, so each
//   SIMD hosts wave s (phase A) and wave s+4 (phase B). Phase B's loop is
//   rotated half a period (prologue QK(0); per iter SMPV(t) then QK(t+1));
//   phase A per iter QK(t) then SMPV(t). One raw s_barrier per tile
//   re-aligns the pair: when A bursts MFMA (QK), B is in exp2/VALU, and
//   vice versa. Slots are balanced (one full tile of work per wave per
//   period). Registers = R12's proven budget (~200: 2 score stages,
//   single kf/vf buffers) under __launch_bounds__(512,2). Barrier counts
//   equal across the divergent paths (32 in-loop + 4 epilogue syncs).
//   Combine zones (34.8 KB) time-shared between phases. Traffic 537 MB,
//   prep, math: identical to passing R12/R18.
//
// MFMA 32x32x16 bf16 layouts (HW-verified):
//   A: A[m=lane&31][k=(lane>>5)*8+j]   B: B[k=(lane>>5)*8+j][n=lane&31]
//   C/D: D[row=(reg&3)+8*(reg>>2)+4*(lane>>5)][col=lane&31]
//
// Kt tile (32 keys): block kc(0..3), lane l, j=0..7 holds
//   K[key=tile*32+(l&31)][d=kc*16+(l>>5)*8+j]          (S^T = K*Q^T A-frag)
// Vt tile: block qq=dt*2+s (0..3), lane l: j=0..3 ->
//   V[key=tile*32+8s+4g+j][d=dt*32+nl]; j=4..7 -> key 16+8s+4g+(j-4)
//   (matches P^T packing: k-slot {0-3,4-7} <-> keys {8s..,16+8s..} per g)

typedef float  f32x4  __attribute__((ext_vector_type(4)));
typedef float  f32x16 __attribute__((ext_vector_type(16)));
typedef short  s16x8  __attribute__((ext_vector_type(8)));
typedef short  s16x4  __attribute__((ext_vector_type(4)));
typedef int    i32x4  __attribute__((ext_vector_type(4)));

#define QSCALE 0.18033688011112042f  /* log2(e)/8 : folds 1/sqrt(64) + exp2 */

__device__ __forceinline__ unsigned short bf16r(float f) {
    unsigned u = __builtin_bit_cast(unsigned, f);
    u += 0x7fffu + ((u >> 16) & 1u);          // round-to-nearest-even
    return (unsigned short)(u >> 16);
}

__device__ __forceinline__ s16x8 cvt8f_scaled(const float* p, float s) {
    f32x4 a = *(const f32x4*)p;
    f32x4 b = *(const f32x4*)(p + 4);
    s16x8 r;
#pragma unroll
    for (int i = 0; i < 4; ++i) {
        r[i]   = (short)bf16r(a[i] * s);
        r[i+4] = (short)bf16r(b[i] * s);
    }
    return r;
}

// pack two f32 -> bf16 pair (lo in [15:0], hi in [31:16]), single VALU op
__device__ __forceinline__ int cvtpk2(float lo, float hi) {
    int r;
    asm("v_cvt_pk_bf16_f32 %0, %1, %2" : "=v"(r) : "v"(lo), "v"(hi));
    return r;
}

// ---- prepass: emit fragment-ordered bf16 tile images for K and V --------
// (identical to passing R9/R11/R12/R16/R18)
__global__ void __launch_bounds__(256)
prep(const float* __restrict__ K, const float* __restrict__ V,
     unsigned short* __restrict__ Kt, unsigned short* __restrict__ Vt) {
    const int t = threadIdx.x, bid = blockIdx.x;
    const int bh = bid & 31, nb = bid >> 5;      // nb: 2 tiles of 32 keys
    const int b = bh >> 4, h = bh & 15;
    const size_t tile0 = ((size_t)bh * 64 + nb * 2) * 2048;   // shorts

    // K: [tile][kc][lane][8] — lane reads 8 consecutive d of one key row
#pragma unroll
    for (int i = 0; i < 2; ++i) {
        const int lin = i * 256 + t;
        const int kbl = lin >> 8, rem = lin & 255;
        const int kc = rem >> 6, l = rem & 63;
        const int nl = l & 31, gg = l >> 5;
        const float* src = K + ((size_t)(b * 2048 + nb * 64 + kbl * 32 + nl)) * 1024
                             + h * 64 + kc * 16 + gg * 8;
        f32x4 a = *(const f32x4*)src;
        f32x4 c = *(const f32x4*)(src + 4);
        i32x4 o = { cvtpk2(a[0], a[1]), cvtpk2(a[2], a[3]),
                    cvtpk2(c[0], c[1]), cvtpk2(c[2], c[3]) };
        *(i32x4*)(Kt + tile0 + kbl * 2048 + kc * 512 + l * 8) = o;
    }

    // V: [tile][qq=dt*2+s][lane][8] — gather 8 keys at one d
#pragma unroll
    for (int i = 0; i < 2; ++i) {
        const int lin = i * 256 + t;
        const int kbl = lin >> 8, rem = lin & 255;
        const int qq = rem >> 6, l = rem & 63;
        const int dt = qq >> 1, s = qq & 1;
        const int nl = l & 31, gg = l >> 5;
        const float* vp0 = V + ((size_t)(b * 2048 + nb * 64 + kbl * 32 + 8 * s + 4 * gg)) * 1024
                             + h * 64 + dt * 32 + nl;
        float x0 = vp0[0],     x1 = vp0[1024],  x2 = vp0[2048],  x3 = vp0[3072];
        float x4 = vp0[16384], x5 = vp0[17408], x6 = vp0[18432], x7 = vp0[19456];
        i32x4 o = { cvtpk2(x0, x1), cvtpk2(x2, x3),
                    cvtpk2(x4, x5), cvtpk2(x6, x7) };
        *(i32x4*)(Vt + tile0 + kbl * 2048 + qq * 512 + l * 8) = o;
    }
}

// ---- main attention kernel ----------------------------------------------
// 256 blocks x 8 waves (512 threads). Block = 256 queries of head bh.
// Wave w: phase = w>>2 (SIMD w&3 hosts one A and one B wave), qsel = w&1,
// ksel = (w>>1)&1. Wave = 64 queries x one key half (32 tiles of 32 keys).
__global__ void __launch_bounds__(512, 2)
attn_fwd(const float* __restrict__ Q, const unsigned short* __restrict__ Kt,
         const unsigned short* __restrict__ Vt, float* __restrict__ O)
{
    __shared__ __align__(16) float ex[2 * 64 * 68];   // 34.8 KB, time-shared

    const int t = threadIdx.x;
    const int w = t >> 6, lane = t & 63;
    const int g = lane >> 5, nl = lane & 31;
    const int phase = w >> 2;
    const int qsel = w & 1, ksel = (w >> 1) & 1;

    const int bid = blockIdx.x;
    const int bh  = bid & 31, qb = bid >> 5;     // XCD = bid&7 = bh&7
    const int b   = bh >> 4,  h  = bh & 15;
    const int q0  = qb * 256 + phase * 128 + qsel * 64;

    // Q B-frags (pre-scaled by log2e/8): qf[qt][kc], q = q0 + qt*32 + nl
    s16x8 qf[2][4];
#pragma unroll
    for (int qt = 0; qt < 2; ++qt) {
        const float* qp = Q + ((size_t)(b * 2048 + q0 + qt * 32 + nl)) * 1024
                            + h * 64 + g * 8;
#pragma unroll
        for (int kc = 0; kc < 4; ++kc)
            qf[qt][kc] = cvt8f_scaled(qp + kc * 16, QSCALE);
    }

    // rolling per-lane tile pointers (advance 2048 shorts = 4KB per tile)
    const unsigned short* kp = Kt + (size_t)bh * 131072 + (size_t)ksel * 65536 + lane * 8;
    const unsigned short* vp = Vt + (size_t)bh * 131072 + (size_t)ksel * 65536 + lane * 8;

    f32x16 oa00 = {}, oa01 = {}, oa10 = {}, oa11 = {};  // oa[dt][qt]
    f32x16 sE0, sE1;                             // score stage (both qt)
    f32x4  lpv0 = {}, lpv1 = {};

    s16x8 kf[4], vf[4];                          // single tile buffer each

    // initial: tile 0 resident; pointers -> tile 1
#pragma unroll
    for (int i = 0; i < 4; ++i) {
        kf[i] = *(const s16x8*)(kp + i * 512);
        vf[i] = *(const s16x8*)(vp + i * 512);
    }
    kp += 2048;
    vp += 2048;

#define REFILL_K do {                                                       \
        _Pragma("unroll")                                                   \
        for (int _i = 0; _i < 4; ++_i)                                      \
            kf[_i] = *(const s16x8*)(kp + _i * 512);                        \
        kp += 2048; } while (0)
#define REFILL_V do {                                                       \
        _Pragma("unroll")                                                   \
        for (int _i = 0; _i < 4; ++_i)                                      \
            vf[_i] = *(const s16x8*)(vp + _i * 512);                        \
        vp += 2048; } while (0)

#define QKT do {                                                            \
        sE0 = (f32x16){}; sE1 = (f32x16){};                                 \
        __builtin_amdgcn_s_setprio(1);                                      \
        _Pragma("unroll")                                                   \
        for (int _kc = 0; _kc < 4; ++_kc) {                                 \
            sE0 = __builtin_amdgcn_mfma_f32_32x32x16_bf16(kf[_kc], qf[0][_kc], sE0, 0, 0, 0); \
            sE1 = __builtin_amdgcn_mfma_f32_32x32x16_bf16(kf[_kc], qf[1][_kc], sE1, 0, 0, 0); \
        }                                                                   \
        __builtin_amdgcn_s_setprio(0); } while (0)

#define SMPV do {                                                           \
        int pk0[8], pk1[8];                                                 \
        _Pragma("unroll")                                                   \
        for (int _c = 0; _c < 4; ++_c) {                                    \
            f32x4 e0 = { __builtin_amdgcn_exp2f(sE0[4*_c]),   __builtin_amdgcn_exp2f(sE0[4*_c+1]),  \
                         __builtin_amdgcn_exp2f(sE0[4*_c+2]), __builtin_amdgcn_exp2f(sE0[4*_c+3]) };\
            f32x4 e1 = { __builtin_amdgcn_exp2f(sE1[4*_c]),   __builtin_amdgcn_exp2f(sE1[4*_c+1]),  \
                         __builtin_amdgcn_exp2f(sE1[4*_c+2]), __builtin_amdgcn_exp2f(sE1[4*_c+3]) };\
            lpv0 += e0; lpv1 += e1;                                         \
            pk0[2*_c]   = cvtpk2(e0[0], e0[1]);  pk0[2*_c+1] = cvtpk2(e0[2], e0[3]); \
            pk1[2*_c]   = cvtpk2(e1[0], e1[1]);  pk1[2*_c+1] = cvtpk2(e1[2], e1[3]); \
        }                                                                   \
        __builtin_amdgcn_s_setprio(1);                                      \
        _Pragma("unroll")                                                   \
        for (int _s = 0; _s < 2; ++_s) {                                    \
            i32x4 b0 = { pk0[_s*2], pk0[_s*2+1], pk0[_s*2+4], pk0[_s*2+5] };\
            i32x4 b1 = { pk1[_s*2], pk1[_s*2+1], pk1[_s*2+4], pk1[_s*2+5] };\
            s16x8 bb0 = __builtin_bit_cast(s16x8, b0);                      \
            s16x8 bb1 = __builtin_bit_cast(s16x8, b1);                      \
            oa00 = __builtin_amdgcn_mfma_f32_32x32x16_bf16(vf[_s],     bb0, oa00, 0, 0, 0); \
            oa10 = __builtin_amdgcn_mfma_f32_32x32x16_bf16(vf[2 + _s], bb0, oa10, 0, 0, 0); \
            oa01 = __builtin_amdgcn_mfma_f32_32x32x16_bf16(vf[_s],     bb1, oa01, 0, 0, 0); \
            oa11 = __builtin_amdgcn_mfma_f32_32x32x16_bf16(vf[2 + _s], bb1, oa11, 0, 0, 0); \
        }                                                                   \
        __builtin_amdgcn_s_setprio(0); } while (0)

    if (phase == 0) {
        // Phase A: per period [barrier][QK(t)][SMPV(t)]
#pragma unroll 1
        for (int it = 0; it < 32; ++it) {
            asm volatile("s_barrier");
            QKT;                                 // kf = tile it
            if (it < 31) REFILL_K;               // kf <- tile it+1
            SMPV;                                // vf = tile it
            if (it < 31) REFILL_V;               // vf <- tile it+1
        }
    } else {
        // Phase B: rotated half a period: [barrier][SMPV(t)][QK(t+1)]
        QKT;                                     // scores(0), kf = tile 0
        REFILL_K;                                // kf <- tile 1
#pragma unroll 1
        for (int it = 0; it < 32; ++it) {
            asm volatile("s_barrier");
            SMPV;                                // finish tile it (vf = it)
            if (it < 31) REFILL_V;               // vf <- tile it+1
            if (it < 31) {
                QKT;                             // scores(it+1), kf = it+1
                if (it < 30) REFILL_K;           // kf <- tile it+2
            }
        }
    }

#undef REFILL_K
#undef REFILL_V
#undef QKT
#undef SMPV

    float lp[2] = { lpv0[0] + lpv0[1] + lpv0[2] + lpv0[3],
                    lpv1[0] + lpv1[1] + lpv1[2] + lpv1[3] };

    // ---- combine key halves, phase-serialized over shared zones ----
    float* zone = ex + qsel * (64 * 68) + lane * 68;   // 272B stride: aligned
#pragma unroll 1
    for (int p = 0; p < 2; ++p) {
        __syncthreads();                         // zones free / loops done
        if (phase == p && ksel) {
#pragma unroll
            for (int i = 0; i < 4; ++i) {
                *(f32x4*)(zone + i * 4) =
                    (f32x4){ oa00[4*i], oa00[4*i+1], oa00[4*i+2], oa00[4*i+3] };
                *(f32x4*)(zone + 16 + i * 4) =
                    (f32x4){ oa01[4*i], oa01[4*i+1], oa01[4*i+2], oa01[4*i+3] };
                *(f32x4*)(zone + 32 + i * 4) =
                    (f32x4){ oa10[4*i], oa10[4*i+1], oa10[4*i+2], oa10[4*i+3] };
                *(f32x4*)(zone + 48 + i * 4) =
                    (f32x4){ oa11[4*i], oa11[4*i+1], oa11[4*i+2], oa11[4*i+3] };
            }
            zone[64] = lp[0];
            zone[65] = lp[1];
        }
        __syncthreads();                         // writes visible
        if (phase == p && !ksel) {
#pragma unroll
            for (int i = 0; i < 4; ++i) {
                f32x4 u0 = *(const f32x4*)(zone + i * 4);
                f32x4 u1 = *(const f32x4*)(zone + 16 + i * 4);
                f32x4 u2 = *(const f32x4*)(zone + 32 + i * 4);
                f32x4 u3 = *(const f32x4*)(zone + 48 + i * 4);
#pragma unroll
                for (int j = 0; j < 4; ++j) {
                    oa00[4*i+j] += u0[j]; oa01[4*i+j] += u1[j];
                    oa10[4*i+j] += u2[j]; oa11[4*i+j] += u3[j];
                }
            }
            float inv[2];
#pragma unroll
            for (int qt = 0; qt < 2; ++qt) {
                float s = lp[qt] + zone[64 + qt];
                s += __shfl_xor(s, 32);          // opposite g-half's keys
                inv[qt] = 1.0f / s;
            }
            float* op0 = O + ((size_t)(b * 2048 + q0 + nl)) * 1024 + h * 64;
            float* op1 = op0 + 32 * 1024;        // q0 + 32 + nl
#pragma unroll
            for (int rq = 0; rq < 4; ++rq) {
                const int d0 = 8 * rq + 4 * g;
                *(f32x4*)(op0 + d0) = (f32x4){
                    oa00[4*rq]   * inv[0], oa00[4*rq+1] * inv[0],
                    oa00[4*rq+2] * inv[0], oa00[4*rq+3] * inv[0] };
                *(f32x4*)(op0 + 32 + d0) = (f32x4){
                    oa10[4*rq]   * inv[0], oa10[4*rq+1] * inv[0],
                    oa10[4*rq+2] * inv[0], oa10[4*rq+3] * inv[0] };
                *(f32x4*)(op1 + d0) = (f32x4){
                    oa01[4*rq]   * inv[1], oa01[4*rq+1] * inv[1],
                    oa01[4*rq+2] * inv[1], oa01[4*rq+3] * inv[1] };
                *(f32x4*)(op1 + 32 + d0) = (f32x4){
                    oa11[4*rq]   * inv[1], oa11[4*rq+1] * inv[1],
                    oa11[4*rq+2] * inv[1], oa11[4*rq+3] * inv[1] };
            }
        }
    }
}

extern "C" void kernel_launch(void* const* d_in, const int* in_sizes, int n_in,
                              void* d_out, int out_size, void* d_ws, size_t ws_size,
                              hipStream_t stream) {
    const float* q = (const float*)d_in[0];
    const float* k = (const float*)d_in[1];
    const float* v = (const float*)d_in[2];
    float* o = (float*)d_out;

    unsigned short* Kt = (unsigned short*)d_ws;   // 8 MB fragment-ordered K tiles
    unsigned short* Vt = Kt + 4194304;            // 8 MB fragment-ordered V tiles

    hipLaunchKernelGGL(prep,     dim3(1024), dim3(256), 0, stream, k, v, Kt, Vt);
    hipLaunchKernelGGL(attn_fwd, dim3(256),  dim3(512), 0, stream, q, Kt, Vt, o);
}